// Round 8
// baseline (325.085 us; speedup 1.0000x reference)
//
#include <hip/hip_runtime.h>
#include <hip/hip_bf16.h>

typedef __hip_bfloat16 bf16;
typedef __attribute__((ext_vector_type(8))) short short8v;   // bf16x8 MFMA fragment
typedef __attribute__((ext_vector_type(4))) float f32x4;     // MFMA accumulator

#define NB   32
#define NTT  512
#define NJ   17
#define ND   128
#define NP   6
#define NH   4
#define NDH  32
#define NBT  (NB*NTT)        // 16384 frames
#define NG   4               // frames per group
#define NTOK (NG*NP)         // 24 tokens per group
#define NMT  2               // M-tiles
#define NTHR 512             // 8 waves
#define GRID 1024            // blocks
#define NITER 4              // groups per block (GRID*NG*NITER == NBT)
#define FSTEP ((long)GRID*NG)        // 4096 frames per iteration step
#define TSTR 136             // bf16 row stride: 272B
#define YSTR 132             // y fp32 row stride

// ws layout: bf16 wgt[81920] | fp32 bc[384] @163840 | u32 mb[16384] @165376
#define WS_WP 0
#define WS_WC 16384
#define WS_WO 65536
#define WS_BC 163840
#define WS_MB 165376

// LDS arena offsets (bytes)
#define OFF_POOL 0            // [24][136] bf16
#define OFF_TOKP 6528         // [24][136] bf16
#define OFF_Q    13056        // [24][136] bf16 ; o overwrites q after PV
#define OFF_K    19584        // [24][136] bf16 ; dead after scores
#define OFF_V    26112        // [24][136] bf16 ; dead after PV
#define OFF_Y    19584        // [24][132] fp32 aliases k|v
#define OFF_PROB 32640        // 576 fp32
#define OFF_MU   34944
#define OFF_INV  35040
#define ARENA_SZ 35136

__device__ __forceinline__ float bf2f(unsigned short u) {
    return __uint_as_float(((unsigned)u) << 16);
}
__device__ __forceinline__ f32x4 MFMA(short8v a, short8v b, f32x4 c) {
    return __builtin_amdgcn_mfma_f32_16x16x32_bf16(a, b, c, 0, 0, 0);
}
__device__ __forceinline__ short8v ldB(const bf16* __restrict__ W, int nt, int ks, int lane) {
    return *reinterpret_cast<const short8v*>(W + (nt*16 + (lane & 15))*ND + ks*32 + ((lane >> 4) << 3));
}
__device__ __forceinline__ short8v ldsA(const bf16* __restrict__ s, int mt, int ks, int lane) {
    int row = mt*16 + (lane & 15);
    if (row >= NTOK) row = NTOK - 1;
    return *reinterpret_cast<const short8v*>(s + row*TSTR + ks*32 + ((lane >> 4) << 3));
}
// LDS-ordering barrier WITHOUT vmcnt drain: global prefetch loads stay in flight.
__device__ __forceinline__ void bsync() {
    asm volatile("s_waitcnt lgkmcnt(0)" ::: "memory");
    __builtin_amdgcn_s_barrier();
    asm volatile("" ::: "memory");
}

// ---- fused prep: wconv + wcomb (LDS-staged, no serial scalar chain) + mconv ----
extern "C" __global__ __launch_bounds__(128)
void prep(const float* __restrict__ Wp, const float* __restrict__ Wi,
          const float* __restrict__ Wo, const float* __restrict__ bp,
          const float* __restrict__ bi, const float* __restrict__ mask,
          bf16* __restrict__ wgt, float* __restrict__ bc,
          unsigned* __restrict__ mbuf) {
    const int b = blockIdx.x, t = threadIdx.x;
    if (b < 384) {               // Wc row b: Wc[b][k] = sum_m Wi[b][m]*Wp[m][k]
        __shared__ float s_wi[128];
        __shared__ float s_red[128];
        s_wi[t] = Wi[b*128 + t];
        __syncthreads();
        float acc = 0.f;
        #pragma unroll 8
        for (int m = 0; m < 128; ++m)
            acc = fmaf(s_wi[m], Wp[m*128 + t], acc);
        wgt[WS_WC + b*128 + t] = __float2bfloat16(acc);
        s_red[t] = s_wi[t] * bp[t];
        __syncthreads();
        #pragma unroll
        for (int s = 64; s > 0; s >>= 1) {
            if (t < s) s_red[t] += s_red[t+s];
            __syncthreads();
        }
        if (t == 0) bc[b] = s_red[0] + bi[b];
    } else {                     // blocks 384..639: wconv + mconv
        int gid = (b - 384)*128 + t;          // 0..32767
        if (gid < 16384) wgt[WS_WP + gid] = __float2bfloat16(Wp[gid]);
        else             wgt[WS_WO + (gid - 16384)] = __float2bfloat16(Wo[gid - 16384]);
        if (gid < 16384) {
            const float* m = mask + (long)gid*NJ;
            unsigned bb = 0;
            #pragma unroll
            for (int j = 0; j < NJ; ++j)
                bb |= (m[j] > 0.05f) ? (1u << j) : 0u;
            mbuf[gid] = bb;
        }
    }
}

// ---- helpers for the main kernel (all-static indexing) ----
__device__ __forceinline__ void prefetch_h(const float* __restrict__ hp,
                                           const unsigned* __restrict__ mp,
                                           float (&hv)[NJ], unsigned &mb) {
    #pragma unroll
    for (int j = 0; j < NJ; ++j) hv[j] = hp[j*ND];   // 17 independent HBM loads
    mb = *mp;
}

__device__ __forceinline__ void stage1_pool(bf16* __restrict__ s_pool,
                                            const float (&hv)[NJ], unsigned mb,
                                            int f, int d) {
    float t[NJ];
    #pragma unroll
    for (int j = 0; j < NJ; ++j) t[j] = (mb >> j & 1) ? hv[j] : 0.f;
    float acc[NP];
    acc[0] = ((t[0]+t[1]) + (t[2]+t[3])) + t[4];
    acc[1] = (t[5]+t[6]) + (t[11]+t[12]);
    acc[2] = t[5]+t[7]+t[9];
    acc[3] = t[6]+t[8]+t[10];
    acc[4] = t[11]+t[13]+t[15];
    acc[5] = t[12]+t[14]+t[16];
    const unsigned pm[NP] = {0x1Fu, 0x1860u, 0x2A0u, 0x540u, 0xA800u, 0x15000u};
    #pragma unroll
    for (int p = 0; p < NP; ++p) {
        float cnt = (float)__popc(mb & pm[p]);
        s_pool[(f*NP+p)*TSTR + d] = __float2bfloat16(acc[p] / fmaxf(cnt, 1e-6f));
    }
}

// Stages 2..7 for one group (assumes s_pool filled; enters after B1; ends with B7).
__device__ __forceinline__ void process_group(
        long frame0, int tid, int lane, int w,
        bf16* s_pool, bf16* s_tokp, bf16* s_q, bf16* s_k, bf16* s_v,
        float* s_y, float* s_probs, float* s_mu, float* s_inv,
        const bf16* __restrict__ wgt, const float* __restrict__ bc,
        const short8v (&bwp)[4],
        const float* __restrict__ b_proj, const float* __restrict__ b_out,
        const float* __restrict__ ln_g, const float* __restrict__ ln_b,
        float* __restrict__ out)
{
    // ---- Stage 2: tok = pool@Wp^T + bp ; qkv = pool@Wc^T + bc ----
    {
        f32x4 acc[NMT];
        acc[0] = (f32x4)(0.f); acc[1] = (f32x4)(0.f);
        #pragma unroll
        for (int ks = 0; ks < 4; ++ks)
            #pragma unroll
            for (int mt = 0; mt < NMT; ++mt)
                acc[mt] = MFMA(ldsA(s_pool, mt, ks, lane), bwp[ks], acc[mt]);
        int col = w*16 + (lane & 15);
        float bv = b_proj[col];
        #pragma unroll
        for (int mt = 0; mt < NMT; ++mt)
            #pragma unroll
            for (int j = 0; j < 4; ++j) {
                int row = mt*16 + ((lane >> 4) << 2) + j;
                if (row < NTOK)
                    s_tokp[row*TSTR + col] = __float2bfloat16(acc[mt][j] + bv);
            }
    }
    #pragma unroll
    for (int t = 0; t < 3; ++t) {           // q, k, v from combined Wc
        int nt = t*8 + w;
        short8v bw[4];
        #pragma unroll
        for (int ks = 0; ks < 4; ++ks) bw[ks] = ldB(wgt + WS_WC, nt, ks, lane);
        f32x4 acc[NMT];
        acc[0] = (f32x4)(0.f); acc[1] = (f32x4)(0.f);
        #pragma unroll
        for (int ks = 0; ks < 4; ++ks)
            #pragma unroll
            for (int mt = 0; mt < NMT; ++mt)
                acc[mt] = MFMA(ldsA(s_pool, mt, ks, lane), bw[ks], acc[mt]);
        bf16* dst = (t == 0) ? s_q : (t == 1) ? s_k : s_v;
        int lcol = w*16 + (lane & 15);
        float bv = bc[nt*16 + (lane & 15)];
        #pragma unroll
        for (int mt = 0; mt < NMT; ++mt)
            #pragma unroll
            for (int j = 0; j < 4; ++j) {
                int row = mt*16 + ((lane >> 4) << 2) + j;
                if (row < NTOK)
                    dst[row*TSTR + lcol] = __float2bfloat16(acc[mt][j] + bv);
            }
    }
    bsync();   // B2

    // ---- Stage 3: scores + softmax -> s_probs ----
    if (tid < NG*NH*NP) {   // 96 threads: (f, h, qi)
        int ff  = tid / (NH*NP);
        int rem = tid - ff*(NH*NP);
        int h   = rem / NP;
        int qi  = rem - h*NP;
        const bf16* qrow = s_q + (ff*NP+qi)*TSTR + h*NDH;
        float sc[NP];
        float mx = -1e30f;
        #pragma unroll
        for (int pk = 0; pk < NP; ++pk) {
            const bf16* krow = s_k + (ff*NP+pk)*TSTR + h*NDH;
            float s = 0.f;
            #pragma unroll
            for (int c = 0; c < NDH; c += 4) {
                ushort4 uq = *reinterpret_cast<const ushort4*>(qrow + c);
                ushort4 uk = *reinterpret_cast<const ushort4*>(krow + c);
                s += bf2f(uq.x)*bf2f(uk.x) + bf2f(uq.y)*bf2f(uk.y)
                   + bf2f(uq.z)*bf2f(uk.z) + bf2f(uq.w)*bf2f(uk.w);
            }
            sc[pk] = s * 0.17677669529663688f;
            mx = fmaxf(mx, sc[pk]);
        }
        float den = 0.f, e[NP];
        #pragma unroll
        for (int pk = 0; pk < NP; ++pk) { e[pk] = __expf(sc[pk]-mx); den += e[pk]; }
        float inv = 1.f/den;
        #pragma unroll
        for (int pk = 0; pk < NP; ++pk)
            s_probs[((ff*NH+h)*NP+qi)*NP + pk] = e[pk]*inv;
    }
    bsync();   // B3

    // ---- Stage 4: part_importance + o = w @ v (o over dead q) ----
    if (tid < NG*NP) {  // 24 threads
        int ff = tid / NP, pk = tid - ff*NP;
        float s = 0.f;
        #pragma unroll
        for (int h = 0; h < NH; ++h)
            #pragma unroll
            for (int q = 0; q < NP; ++q)
                s += s_probs[((ff*NH+h)*NP+q)*NP + pk];
        out[(long)NBT*NP*ND + (frame0+ff)*NP + pk] = s * (1.f/24.f);
    }
    #pragma unroll
    for (int i = 0; i < (NTOK*ND)/NTHR; ++i) {   // 6 iters
        int idx = i*NTHR + tid;
        int token = idx >> 7;
        int dd = idx & (ND-1);
        int ff = token / NP, qi = token - ff*NP;
        int h = dd >> 5;
        const float* pr = s_probs + ((ff*NH+h)*NP+qi)*NP;
        float s = 0.f;
        #pragma unroll
        for (int pk = 0; pk < NP; ++pk) {
            float v = bf2f(reinterpret_cast<const unsigned short*>(s_v)[(ff*NP+pk)*TSTR + dd]);
            s += pr[pk]*v;
        }
        s_q[token*TSTR + dd] = __float2bfloat16(s);
    }
    bsync();   // B4

    // ---- Stage 5: y = o @ Wo^T + b_out + tok -> fp32 y over dead k|v ----
    {
        short8v bo[4];
        #pragma unroll
        for (int ks = 0; ks < 4; ++ks) bo[ks] = ldB(wgt + WS_WO, w, ks, lane);
        f32x4 acc[NMT];
        acc[0] = (f32x4)(0.f); acc[1] = (f32x4)(0.f);
        #pragma unroll
        for (int ks = 0; ks < 4; ++ks)
            #pragma unroll
            for (int mt = 0; mt < NMT; ++mt)
                acc[mt] = MFMA(ldsA(s_q, mt, ks, lane), bo[ks], acc[mt]);
        int col = w*16 + (lane & 15);
        float bv = b_out[col];
        #pragma unroll
        for (int mt = 0; mt < NMT; ++mt)
            #pragma unroll
            for (int j = 0; j < 4; ++j) {
                int row = mt*16 + ((lane >> 4) << 2) + j;
                if (row < NTOK) {
                    float resid = bf2f(*reinterpret_cast<const unsigned short*>(&s_tokp[row*TSTR + col]));
                    s_y[row*YSTR + col] = acc[mt][j] + bv + resid;
                }
            }
    }
    bsync();   // B5

    // ---- Stage 6: LayerNorm stats ----
    if (tid < NTOK*4) {   // 96 threads
        int token = tid >> 2, sub = tid & 3;
        const float* row = s_y + token*YSTR + sub*NDH;
        float s = 0.f, s2 = 0.f;
        #pragma unroll
        for (int j = 0; j < NDH; j += 4) {
            float4 v = *reinterpret_cast<const float4*>(row + j);
            s  += v.x + v.y + v.z + v.w;
            s2 += v.x*v.x + v.y*v.y + v.z*v.z + v.w*v.w;
        }
        s  += __shfl_xor(s, 1);  s  += __shfl_xor(s, 2);
        s2 += __shfl_xor(s2, 1); s2 += __shfl_xor(s2, 2);
        float mean = s * (1.f/128.f);
        float var  = s2 * (1.f/128.f) - mean*mean;
        if (sub == 0) {
            s_mu[token]  = mean;
            s_inv[token] = rsqrtf(var + 1e-5f);
        }
    }
    bsync();   // B6

    // ---- Stage 7: normalize + store ----
    #pragma unroll
    for (int i = 0; i < 2; ++i) {
        int idx4 = i*NTHR + tid;
        if (idx4 < NTOK*(ND/4)) {
            int token = idx4 >> 5;
            int dj = (idx4 & 31) << 2;
            float mean = s_mu[token], inv = s_inv[token];
            float4 v = *reinterpret_cast<const float4*>(s_y + token*YSTR + dj);
            float4 g = *reinterpret_cast<const float4*>(ln_g + dj);
            float4 b = *reinterpret_cast<const float4*>(ln_b + dj);
            float4 r;
            r.x = (v.x-mean)*inv*g.x + b.x;
            r.y = (v.y-mean)*inv*g.y + b.y;
            r.z = (v.z-mean)*inv*g.z + b.z;
            r.w = (v.w-mean)*inv*g.w + b.w;
            *reinterpret_cast<float4*>(out + (frame0*NP + token)*(long)ND + dj) = r;
        }
    }
    bsync();   // B7: y (k|v) reads done before next iter's stage-2 writes
}

extern "C" __global__ __launch_bounds__(NTHR, 6)
void bpa_fused(const float* __restrict__ h_joint,
               const bf16* __restrict__ wgt, const float* __restrict__ bc,
               const unsigned* __restrict__ mbuf,
               const float* __restrict__ b_proj, const float* __restrict__ b_out,
               const float* __restrict__ ln_g,  const float* __restrict__ ln_b,
               float* __restrict__ out)
{
    __shared__ __align__(16) unsigned char s_arena[ARENA_SZ];
    bf16*  s_pool  = reinterpret_cast<bf16*>(s_arena + OFF_POOL);
    bf16*  s_tokp  = reinterpret_cast<bf16*>(s_arena + OFF_TOKP);
    bf16*  s_q     = reinterpret_cast<bf16*>(s_arena + OFF_Q);
    bf16*  s_k     = reinterpret_cast<bf16*>(s_arena + OFF_K);
    bf16*  s_v     = reinterpret_cast<bf16*>(s_arena + OFF_V);
    float* s_y     = reinterpret_cast<float*>(s_arena + OFF_Y);
    float* s_probs = reinterpret_cast<float*>(s_arena + OFF_PROB);
    float* s_mu    = reinterpret_cast<float*>(s_arena + OFF_MU);
    float* s_inv   = reinterpret_cast<float*>(s_arena + OFF_INV);

    const int tid  = threadIdx.x;
    const int lane = tid & 63;
    const int w    = tid >> 6;                          // wave 0..7
    const int f    = tid >> 7;                          // frame-in-group 0..3
    const int d    = tid & (ND-1);                      // column 0..127

    const long base  = (long)blockIdx.x * NG;           // frame0 of iteration 0
    const long fr0   = base + f;
    const float* hb0 = h_joint + fr0*(long)(NJ*ND) + d;
    const long HSTEP = FSTEP*(long)(NJ*ND);

    // Loop-invariant W_proj B-fragments (16 VGPR).
    short8v bwp[4];
    #pragma unroll
    for (int ks = 0; ks < 4; ++ks) bwp[ks] = ldB(wgt + WS_WP, w, ks, lane);

    // Named double buffers — every access compile-time indexed (no scratch).
    float hvA[NJ], hvB[NJ];
    unsigned mbA, mbB;
    prefetch_h(hb0, mbuf + fr0, hvA, mbA);

    // ---- it 0: consume A, prefetch B ----
    stage1_pool(s_pool, hvA, mbA, f, d);
    prefetch_h(hb0 + 1*HSTEP, mbuf + fr0 + 1*FSTEP, hvB, mbB);
    bsync();   // B1
    process_group(base + 0*FSTEP, tid, lane, w, s_pool, s_tokp, s_q, s_k, s_v,
                  s_y, s_probs, s_mu, s_inv, wgt, bc, bwp, b_proj, b_out,
                  ln_g, ln_b, out);
    // ---- it 1: consume B, prefetch A ----
    stage1_pool(s_pool, hvB, mbB, f, d);
    prefetch_h(hb0 + 2*HSTEP, mbuf + fr0 + 2*FSTEP, hvA, mbA);
    bsync();
    process_group(base + 1*FSTEP, tid, lane, w, s_pool, s_tokp, s_q, s_k, s_v,
                  s_y, s_probs, s_mu, s_inv, wgt, bc, bwp, b_proj, b_out,
                  ln_g, ln_b, out);
    // ---- it 2: consume A, prefetch B ----
    stage1_pool(s_pool, hvA, mbA, f, d);
    prefetch_h(hb0 + 3*HSTEP, mbuf + fr0 + 3*FSTEP, hvB, mbB);
    bsync();
    process_group(base + 2*FSTEP, tid, lane, w, s_pool, s_tokp, s_q, s_k, s_v,
                  s_y, s_probs, s_mu, s_inv, wgt, bc, bwp, b_proj, b_out,
                  ln_g, ln_b, out);
    // ---- it 3: consume B, no prefetch ----
    stage1_pool(s_pool, hvB, mbB, f, d);
    bsync();
    process_group(base + 3*FSTEP, tid, lane, w, s_pool, s_tokp, s_q, s_k, s_v,
                  s_y, s_probs, s_mu, s_inv, wgt, bc, bwp, b_proj, b_out,
                  ln_g, ln_b, out);
}

extern "C" void kernel_launch(void* const* d_in, const int* in_sizes, int n_in,
                              void* d_out, int out_size, void* d_ws, size_t ws_size,
                              hipStream_t stream) {
    const float* h_joint = (const float*)d_in[0];
    const float* mask    = (const float*)d_in[1];
    const float* W_proj  = (const float*)d_in[2];
    const float* b_proj  = (const float*)d_in[3];
    const float* W_in    = (const float*)d_in[4];
    const float* b_in    = (const float*)d_in[5];
    const float* W_out   = (const float*)d_in[6];
    const float* b_out   = (const float*)d_in[7];
    const float* ln_g    = (const float*)d_in[8];
    const float* ln_b    = (const float*)d_in[9];
    float* out = (float*)d_out;
    bf16*     wgt  = (bf16*)d_ws;
    float*    bc   = (float*)((char*)d_ws + WS_BC);
    unsigned* mbuf = (unsigned*)((char*)d_ws + WS_MB);

    hipLaunchKernelGGL(prep, dim3(640), dim3(128), 0, stream,
                       W_proj, W_in, W_out, b_proj, b_in, mask, wgt, bc, mbuf);
    hipLaunchKernelGGL(bpa_fused, dim3(GRID), dim3(NTHR), 0, stream,
                       h_joint, wgt, bc, mbuf, b_proj, b_out, ln_g, ln_b, out);
}

// Round 9
// 316.798 us; speedup vs baseline: 1.0262x; 1.0262x over previous
//
#include <hip/hip_runtime.h>
#include <hip/hip_bf16.h>

typedef __hip_bfloat16 bf16;
typedef __attribute__((ext_vector_type(8))) short short8v;   // bf16x8 MFMA fragment
typedef __attribute__((ext_vector_type(4))) float f32x4;     // MFMA accumulator

#define NJ   17
#define ND   128
#define NP   6
#define NH   4
#define NBT  16384
#define NTHR 256             // 4 waves
#define NWAVE 4
#define GRID (NBT/NWAVE)     // 4096 blocks, 1 frame per wave
#define RSTR 136             // LDS row stride (bf16 elems) = 272 B

// ws layout: bf16 wgt[81920] | fp32 bc[384] @163840 | u32 mb[16384] @165376
#define WS_WP 0
#define WS_WC 16384
#define WS_WO 65536
#define WS_BC 163840
#define WS_MB 165376

// per-wave LDS arena (byte offsets)
#define A_POOL 0             // [6][136] bf16 ; reused for o after PV
#define A_Q    1632          // [6][136] bf16
#define A_K    3264          // [6][136] bf16
#define A_V    4896          // [6][136] bf16
#define A_PR   6528          // [4][6][6] f32 probs = 576 B
#define WARENA 7168          // padded, 16B-aligned

__device__ __forceinline__ float bf2f(unsigned short u) {
    return __uint_as_float(((unsigned)u) << 16);
}
__device__ __forceinline__ unsigned pk2(float x, float y) {
    bf16 bx = __float2bfloat16(x), by = __float2bfloat16(y);
    unsigned short ux = *reinterpret_cast<unsigned short*>(&bx);
    unsigned short uy = *reinterpret_cast<unsigned short*>(&by);
    return ((unsigned)uy << 16) | ux;
}
__device__ __forceinline__ f32x4 MFMA(short8v a, short8v b, f32x4 c) {
    return __builtin_amdgcn_mfma_f32_16x16x32_bf16(a, b, c, 0, 0, 0);
}
// B-fragment from bf16 weight (row-major [dout][k] == B^T): one 16B load.
__device__ __forceinline__ short8v ldB(const bf16* __restrict__ W, int nt, int ks, int lane) {
    return *reinterpret_cast<const short8v*>(W + (nt*16 + (lane & 15))*ND + ks*32 + ((lane >> 4) << 3));
}
// A-fragment from a [6][RSTR] wave-local tile; rows >= 6 clamp to 5 (results discarded).
__device__ __forceinline__ short8v ldsA6(const bf16* __restrict__ s, int ks, int lane) {
    int row = lane & 15;
    if (row > 5) row = 5;
    return *reinterpret_cast<const short8v*>(s + row*RSTR + ks*32 + ((lane >> 4) << 3));
}
// Intra-wave LDS write->read fence: no s_barrier, loads elsewhere stay in flight.
#define WFENCE() do { \
    asm volatile("s_waitcnt lgkmcnt(0)" ::: "memory"); \
    __builtin_amdgcn_sched_barrier(0); \
} while (0)

// ---- fused prep: Wp/Wo bf16 conversion + Wc = Win@Wp + bc + mask bitmasks ----
extern "C" __global__ __launch_bounds__(128)
void prep(const float* __restrict__ Wp, const float* __restrict__ Wi,
          const float* __restrict__ Wo, const float* __restrict__ bp,
          const float* __restrict__ bi, const float* __restrict__ mask,
          bf16* __restrict__ wgt, float* __restrict__ bc,
          unsigned* __restrict__ mbuf) {
    const int b = blockIdx.x, t = threadIdx.x;
    if (b < 384) {               // Wc row b: Wc[b][k] = sum_m Wi[b][m]*Wp[m][k]
        __shared__ float s_wi[128];
        __shared__ float s_red[128];
        s_wi[t] = Wi[b*128 + t];
        __syncthreads();
        float acc = 0.f;
        #pragma unroll 8
        for (int m = 0; m < 128; ++m)
            acc = fmaf(s_wi[m], Wp[m*128 + t], acc);
        wgt[WS_WC + b*128 + t] = __float2bfloat16(acc);
        s_red[t] = s_wi[t] * bp[t];
        __syncthreads();
        #pragma unroll
        for (int s = 64; s > 0; s >>= 1) {
            if (t < s) s_red[t] += s_red[t+s];
            __syncthreads();
        }
        if (t == 0) bc[b] = s_red[0] + bi[b];
    } else {                     // blocks 384..639: weight conversion + mask bits
        int gid = (b - 384)*128 + t;          // 0..32767
        if (gid < 16384) wgt[WS_WP + gid] = __float2bfloat16(Wp[gid]);
        else             wgt[WS_WO + (gid - 16384)] = __float2bfloat16(Wo[gid - 16384]);
        if (gid < 16384) {
            const float* m = mask + (long)gid*NJ;
            unsigned bb = 0;
            #pragma unroll
            for (int j = 0; j < NJ; ++j)
                bb |= (m[j] > 0.05f) ? (1u << j) : 0u;
            mbuf[gid] = bb;
        }
    }
}

extern "C" __global__ __launch_bounds__(NTHR)
void bpa_wave(const float* __restrict__ h_joint,
              const bf16* __restrict__ wgt, const float* __restrict__ bc,
              const unsigned* __restrict__ mbuf,
              const float* __restrict__ b_proj, const float* __restrict__ b_out,
              const float* __restrict__ ln_g,  const float* __restrict__ ln_b,
              float* __restrict__ out)
{
    __shared__ __align__(16) unsigned char s_arena[NWAVE*WARENA];
    const int tid  = threadIdx.x;
    const int lane = tid & 63;
    const int wid  = tid >> 6;
    unsigned char* wa = s_arena + wid*WARENA;
    bf16*  s_pool = reinterpret_cast<bf16*>(wa + A_POOL);   // pooled tokens; later o
    bf16*  s_q    = reinterpret_cast<bf16*>(wa + A_Q);
    bf16*  s_k    = reinterpret_cast<bf16*>(wa + A_K);
    bf16*  s_v    = reinterpret_cast<bf16*>(wa + A_V);
    float* s_pr   = reinterpret_cast<float*>(wa + A_PR);

    const long frame = (long)blockIdx.x*NWAVE + wid;
    const int l15 = lane & 15;
    const int lhi = lane >> 4;                              // 0..3

    // ---- preload per-lane column params (L2-hot, same addrs for all waves) ----
    float lg[8], lb[8], bb[8];
    #pragma unroll
    for (int nt = 0; nt < 8; ++nt) {
        int col = nt*16 + l15;
        lg[nt] = ln_g[col];
        lb[nt] = ln_b[col];
        bb[nt] = b_proj[col] + b_out[col];   // combined bias for y
    }

    // ---- Stage 1: pooling (lane owns cols c0, c0+1) ----
    const int c0 = lane*2;
    {
        const float* hp = h_joint + frame*(long)(NJ*ND) + c0;
        float2 hv[NJ];
        #pragma unroll
        for (int j = 0; j < NJ; ++j)
            hv[j] = *reinterpret_cast<const float2*>(hp + j*ND);   // 17 independent loads
        unsigned mb = mbuf[frame];
        #pragma unroll
        for (int j = 0; j < NJ; ++j) {
            bool on = (mb >> j) & 1;
            hv[j].x = on ? hv[j].x : 0.f;
            hv[j].y = on ? hv[j].y : 0.f;
        }
        float2 a[NP];
        a[0].x = ((hv[0].x+hv[1].x) + (hv[2].x+hv[3].x)) + hv[4].x;
        a[0].y = ((hv[0].y+hv[1].y) + (hv[2].y+hv[3].y)) + hv[4].y;
        a[1].x = (hv[5].x+hv[6].x) + (hv[11].x+hv[12].x);
        a[1].y = (hv[5].y+hv[6].y) + (hv[11].y+hv[12].y);
        a[2].x = hv[5].x+hv[7].x+hv[9].x;   a[2].y = hv[5].y+hv[7].y+hv[9].y;
        a[3].x = hv[6].x+hv[8].x+hv[10].x;  a[3].y = hv[6].y+hv[8].y+hv[10].y;
        a[4].x = hv[11].x+hv[13].x+hv[15].x; a[4].y = hv[11].y+hv[13].y+hv[15].y;
        a[5].x = hv[12].x+hv[14].x+hv[16].x; a[5].y = hv[12].y+hv[14].y+hv[16].y;
        const unsigned pm[NP] = {0x1Fu, 0x1860u, 0x2A0u, 0x540u, 0xA800u, 0x15000u};
        #pragma unroll
        for (int p = 0; p < NP; ++p) {
            float inv = 1.f / fmaxf((float)__popc(mb & pm[p]), 1e-6f);
            *reinterpret_cast<unsigned*>(&s_pool[p*RSTR + c0]) = pk2(a[p].x*inv, a[p].y*inv);
        }
    }
    WFENCE();   // pool visible to all lanes of this wave

    // ---- Stage 2: tok (registers) + qkv (LDS) via MFMA, M=6 ----
    short8v ap[4];
    #pragma unroll
    for (int ks = 0; ks < 4; ++ks) ap[ks] = ldsA6(s_pool, ks, lane);

    f32x4 tk[8];                                // tok C-fragments, resid for y
    #pragma unroll
    for (int nt = 0; nt < 8; ++nt) {
        f32x4 acc = (f32x4)(0.f);
        #pragma unroll
        for (int ks = 0; ks < 4; ++ks)
            acc = MFMA(ap[ks], ldB(wgt + WS_WP, nt, ks, lane), acc);
        tk[nt] = acc;
    }
    #pragma unroll
    for (int t = 0; t < 3; ++t) {               // q, k, v from combined Wc
        bf16* dst = (t == 0) ? s_q : (t == 1) ? s_k : s_v;
        #pragma unroll
        for (int ntl = 0; ntl < 8; ++ntl) {
            int nt = t*8 + ntl;
            f32x4 acc = (f32x4)(0.f);
            #pragma unroll
            for (int ks = 0; ks < 4; ++ks)
                acc = MFMA(ap[ks], ldB(wgt + WS_WC, nt, ks, lane), acc);
            float bv = bc[nt*16 + l15];
            #pragma unroll
            for (int j = 0; j < 4; ++j) {
                int row = lhi*4 + j;
                if (row < NP)
                    dst[row*RSTR + ntl*16 + l15] = __float2bfloat16(acc[j] + bv);
            }
        }
    }
    WFENCE();   // q,k,v visible

    // ---- Stage 3: scores + softmax (lanes 0..23 = (h,qi)) -> probs ----
    if (lane < NH*NP) {
        int h  = lane / NP;
        int qi = lane - h*NP;
        const bf16* qrow = s_q + qi*RSTR + h*32;
        float sc[NP];
        float mx = -1e30f;
        #pragma unroll
        for (int pk = 0; pk < NP; ++pk) {
            const bf16* krow = s_k + pk*RSTR + h*32;
            float s = 0.f;
            #pragma unroll
            for (int c = 0; c < 32; c += 4) {
                ushort4 uq = *reinterpret_cast<const ushort4*>(qrow + c);
                ushort4 uk = *reinterpret_cast<const ushort4*>(krow + c);
                s += bf2f(uq.x)*bf2f(uk.x) + bf2f(uq.y)*bf2f(uk.y)
                   + bf2f(uq.z)*bf2f(uk.z) + bf2f(uq.w)*bf2f(uk.w);
            }
            sc[pk] = s * 0.17677669529663688f;   // 1/sqrt(32)
            mx = fmaxf(mx, sc[pk]);
        }
        float e[NP], den = 0.f;
        #pragma unroll
        for (int pk = 0; pk < NP; ++pk) { e[pk] = __expf(sc[pk]-mx); den += e[pk]; }
        float inv = 1.f/den;
        float* pr = s_pr + (h*NP + qi)*NP;
        *reinterpret_cast<float2*>(pr + 0) = make_float2(e[0]*inv, e[1]*inv);
        *reinterpret_cast<float2*>(pr + 2) = make_float2(e[2]*inv, e[3]*inv);
        *reinterpret_cast<float2*>(pr + 4) = make_float2(e[4]*inv, e[5]*inv);
    }
    WFENCE();   // probs visible

    // ---- Stage 4: part_importance (lanes 0..5) + PV (all lanes) ----
    if (lane < NP) {
        float s = 0.f;
        #pragma unroll
        for (int h = 0; h < NH; ++h)
            #pragma unroll
            for (int q = 0; q < NP; ++q)
                s += s_pr[(h*NP+q)*NP + lane];
        out[(long)NBT*NP*ND + frame*NP + lane] = s * (1.f/24.f);
    }
    {
        const int h = lhi;                       // c0>>5 == lane>>4
        const float* pr = s_pr + h*NP*NP;
        float vx[NP], vy[NP];
        #pragma unroll
        for (int pk = 0; pk < NP; ++pk) {
            unsigned vv = *reinterpret_cast<const unsigned*>(&s_v[pk*RSTR + c0]);
            vx[pk] = bf2f((unsigned short)(vv & 0xFFFF));
            vy[pk] = bf2f((unsigned short)(vv >> 16));
        }
        #pragma unroll
        for (int qi = 0; qi < NP; ++qi) {
            float2 p01 = *reinterpret_cast<const float2*>(pr + qi*NP + 0);
            float2 p23 = *reinterpret_cast<const float2*>(pr + qi*NP + 2);
            float2 p45 = *reinterpret_cast<const float2*>(pr + qi*NP + 4);
            float ox = p01.x*vx[0] + p01.y*vx[1] + p23.x*vx[2]
                     + p23.y*vx[3] + p45.x*vx[4] + p45.y*vx[5];
            float oy = p01.x*vy[0] + p01.y*vy[1] + p23.x*vy[2]
                     + p23.y*vy[3] + p45.x*vy[4] + p45.y*vy[5];
            *reinterpret_cast<unsigned*>(&s_pool[qi*RSTR + c0]) = pk2(ox, oy);  // o over pool
        }
    }
    WFENCE();   // o visible

    // ---- Stage 5: y = o@Wo^T + tok + (bp+bo)  (registers) ----
    short8v ao[4];
    #pragma unroll
    for (int ks = 0; ks < 4; ++ks) ao[ks] = ldsA6(s_pool, ks, lane);
    f32x4 y[8];
    #pragma unroll
    for (int nt = 0; nt < 8; ++nt) {
        f32x4 acc = (f32x4)(0.f);
        #pragma unroll
        for (int ks = 0; ks < 4; ++ks)
            acc = MFMA(ao[ks], ldB(wgt + WS_WO, nt, ks, lane), acc);
        #pragma unroll
        for (int j = 0; j < 4; ++j)
            y[nt][j] = acc[j] + tk[nt][j] + bb[nt];
    }

    // ---- Stage 6: LayerNorm stats via 16-lane butterfly (row r = lhi*4+j) ----
    float mean[4], rinv[4];
    #pragma unroll
    for (int j = 0; j < 4; ++j) {
        float s = 0.f, s2 = 0.f;
        #pragma unroll
        for (int nt = 0; nt < 8; ++nt) {
            float v = y[nt][j];
            s += v; s2 += v*v;
        }
        s  += __shfl_xor(s, 1);  s  += __shfl_xor(s, 2);
        s  += __shfl_xor(s, 4);  s  += __shfl_xor(s, 8);
        s2 += __shfl_xor(s2, 1); s2 += __shfl_xor(s2, 2);
        s2 += __shfl_xor(s2, 4); s2 += __shfl_xor(s2, 8);
        float m = s * (1.f/128.f);
        mean[j] = m;
        rinv[j] = rsqrtf(s2 * (1.f/128.f) - m*m + 1e-5f);
    }

    // ---- Stage 7: normalize + store (rows < 6 only) ----
    #pragma unroll
    for (int j = 0; j < 4; ++j) {
        int r = lhi*4 + j;
        if (r < NP) {
            float* orow = out + (frame*NP + r)*(long)ND + l15;
            #pragma unroll
            for (int nt = 0; nt < 8; ++nt)
                orow[nt*16] = (y[nt][j] - mean[j])*rinv[j]*lg[nt] + lb[nt];
        }
    }
}

extern "C" void kernel_launch(void* const* d_in, const int* in_sizes, int n_in,
                              void* d_out, int out_size, void* d_ws, size_t ws_size,
                              hipStream_t stream) {
    const float* h_joint = (const float*)d_in[0];
    const float* mask    = (const float*)d_in[1];
    const float* W_proj  = (const float*)d_in[2];
    const float* b_proj  = (const float*)d_in[3];
    const float* W_in    = (const float*)d_in[4];
    const float* b_in    = (const float*)d_in[5];
    const float* W_out   = (const float*)d_in[6];
    const float* b_out   = (const float*)d_in[7];
    const float* ln_g    = (const float*)d_in[8];
    const float* ln_b    = (const float*)d_in[9];
    float* out = (float*)d_out;
    bf16*     wgt  = (bf16*)d_ws;
    float*    bc   = (float*)((char*)d_ws + WS_BC);
    unsigned* mbuf = (unsigned*)((char*)d_ws + WS_MB);

    hipLaunchKernelGGL(prep, dim3(640), dim3(128), 0, stream,
                       W_proj, W_in, W_out, b_proj, b_in, mask, wgt, bc, mbuf);
    hipLaunchKernelGGL(bpa_wave, dim3(GRID), dim3(NTHR), 0, stream,
                       h_joint, wgt, bc, mbuf, b_proj, b_out, ln_g, ln_b, out);
}

// Round 10
// 119.816 us; speedup vs baseline: 2.7132x; 2.6440x over previous
//
#include <hip/hip_runtime.h>
#include <hip/hip_bf16.h>

typedef __hip_bfloat16 bf16;
typedef __attribute__((ext_vector_type(8))) short short8v;   // bf16x8 MFMA fragment
typedef __attribute__((ext_vector_type(4))) float f32x4;     // MFMA accumulator

#define NJ   17
#define ND   128
#define NP   6
#define NH   4
#define NBT  16384
#define NG   4               // frames per block
#define NTOK (NG*NP)         // 24 tokens
#define NTHR 512             // 8 waves
#define GRID (NBT/NG)        // 4096 blocks
#define TSTR 136             // bf16 row stride: 272B
#define YSTR 132             // y fp32 row stride

// ws layout: bf16 wgt[81920] | fp32 bc[384] @163840 | u32 mb[16384] @165376
#define WS_WP 0
#define WS_WC 16384
#define WS_WO 65536
#define WS_BC 163840
#define WS_MB 165376

// LDS arena offsets (bytes)
#define OFF_POOL 0            // [24][136] bf16
#define OFF_TOKP 6528         // [24][136] bf16 (residual)
#define OFF_Q    13056        // [24][136] bf16 ; o overwrites q after PV
#define OFF_K    19584        // [24][136] bf16 ; dead after scores
#define OFF_V    26112        // [24][136] bf16 ; dead after PV
#define OFF_Y    19584        // [24][132] fp32 aliases k|v
#define OFF_PROB 32640        // [4][4][6][6] fp32 = 2304 B
#define OFF_MU   34944
#define OFF_INV  35040
#define ARENA_SZ 35136

__device__ __forceinline__ float bf2f(unsigned short u) {
    return __uint_as_float(((unsigned)u) << 16);
}
__device__ __forceinline__ unsigned pk2(float x, float y) {
    bf16 bx = __float2bfloat16(x), by = __float2bfloat16(y);
    unsigned short ux = *reinterpret_cast<unsigned short*>(&bx);
    unsigned short uy = *reinterpret_cast<unsigned short*>(&by);
    return ((unsigned)uy << 16) | ux;
}
__device__ __forceinline__ f32x4 MFMA(short8v a, short8v b, f32x4 c) {
    return __builtin_amdgcn_mfma_f32_16x16x32_bf16(a, b, c, 0, 0, 0);
}
__device__ __forceinline__ short8v ldB(const bf16* __restrict__ W, int nt, int ks, int lane) {
    return *reinterpret_cast<const short8v*>(W + (nt*16 + (lane & 15))*ND + ks*32 + ((lane >> 4) << 3));
}
__device__ __forceinline__ short8v ldsA(const bf16* __restrict__ s, int mt, int ks, int lane) {
    int row = mt*16 + (lane & 15);
    if (row >= NTOK) row = NTOK - 1;
    return *reinterpret_cast<const short8v*>(s + row*TSTR + ks*32 + ((lane >> 4) << 3));
}
// Block barrier with LDS ordering only — global loads stay in flight.
__device__ __forceinline__ void bsync() {
    asm volatile("s_waitcnt lgkmcnt(0)" ::: "memory");
    __builtin_amdgcn_s_barrier();
    asm volatile("" ::: "memory");
}
// Intra-wave LDS write->read fence (rule #18: sched_barrier after lgkmcnt).
#define WFENCE() do { \
    asm volatile("s_waitcnt lgkmcnt(0)" ::: "memory"); \
    __builtin_amdgcn_sched_barrier(0); \
} while (0)

// ---- fused prep (R8, validated): Wp/Wo bf16 + Wc = Win@Wp + bc + mask bits ----
extern "C" __global__ __launch_bounds__(128)
void prep(const float* __restrict__ Wp, const float* __restrict__ Wi,
          const float* __restrict__ Wo, const float* __restrict__ bp,
          const float* __restrict__ bi, const float* __restrict__ mask,
          bf16* __restrict__ wgt, float* __restrict__ bc,
          unsigned* __restrict__ mbuf) {
    const int b = blockIdx.x, t = threadIdx.x;
    if (b < 384) {
        __shared__ float s_wi[128];
        __shared__ float s_red[128];
        s_wi[t] = Wi[b*128 + t];
        __syncthreads();
        float acc = 0.f;
        #pragma unroll 8
        for (int m = 0; m < 128; ++m)
            acc = fmaf(s_wi[m], Wp[m*128 + t], acc);
        wgt[WS_WC + b*128 + t] = __float2bfloat16(acc);
        s_red[t] = s_wi[t] * bp[t];
        __syncthreads();
        #pragma unroll
        for (int s = 64; s > 0; s >>= 1) {
            if (t < s) s_red[t] += s_red[t+s];
            __syncthreads();
        }
        if (t == 0) bc[b] = s_red[0] + bi[b];
    } else {
        int gid = (b - 384)*128 + t;          // 0..32767
        if (gid < 16384) wgt[WS_WP + gid] = __float2bfloat16(Wp[gid]);
        else             wgt[WS_WO + (gid - 16384)] = __float2bfloat16(Wo[gid - 16384]);
        if (gid < 16384) {
            const float* m = mask + (long)gid*NJ;
            unsigned bb = 0;
            #pragma unroll
            for (int j = 0; j < NJ; ++j)
                bb |= (m[j] > 0.05f) ? (1u << j) : 0u;
            mbuf[gid] = bb;
        }
    }
}

// Store a 24-row C column slice (2 M-tiles) to a [24][TSTR] bf16 buffer.
__device__ __forceinline__ void st24(bf16* __restrict__ dst, const f32x4 &a0,
                                     const f32x4 &a1, float bv, int col, int lhi) {
    #pragma unroll
    for (int j = 0; j < 4; ++j) {
        int r0 = lhi*4 + j;
        dst[r0*TSTR + col] = __float2bfloat16(a0[j] + bv);
        int r1 = 16 + lhi*4 + j;
        if (r1 < NTOK) dst[r1*TSTR + col] = __float2bfloat16(a1[j] + bv);
    }
}

extern "C" __global__ __launch_bounds__(NTHR, 6)
void bpa_fused(const float* __restrict__ h_joint,
               const bf16* __restrict__ wgt, const float* __restrict__ bc,
               const unsigned* __restrict__ mbuf,
               const float* __restrict__ b_proj, const float* __restrict__ b_out,
               const float* __restrict__ ln_g,  const float* __restrict__ ln_b,
               float* __restrict__ out)
{
    __shared__ __align__(16) unsigned char s_arena[ARENA_SZ];
    bf16*  s_pool  = reinterpret_cast<bf16*>(s_arena + OFF_POOL);
    bf16*  s_tokp  = reinterpret_cast<bf16*>(s_arena + OFF_TOKP);
    bf16*  s_q     = reinterpret_cast<bf16*>(s_arena + OFF_Q);
    bf16*  s_k     = reinterpret_cast<bf16*>(s_arena + OFF_K);
    bf16*  s_v     = reinterpret_cast<bf16*>(s_arena + OFF_V);
    float* s_y     = reinterpret_cast<float*>(s_arena + OFF_Y);
    float* s_probs = reinterpret_cast<float*>(s_arena + OFF_PROB);
    float* s_mu    = reinterpret_cast<float*>(s_arena + OFF_MU);
    float* s_inv   = reinterpret_cast<float*>(s_arena + OFF_INV);

    const int tid  = threadIdx.x;
    const int lane = tid & 63;
    const int w    = tid >> 6;                          // wave 0..7
    const int l15  = lane & 15;
    const int lhi  = lane >> 4;                         // 0..3
    const long frame0 = (long)blockIdx.x * NG;

    // ---- Stage 1: pooling (thread = (frame f, col d)), unconditional loads ----
    {
        const int f = tid >> 7;
        const int d = tid & (ND-1);
        const float* hcol = h_joint + (frame0 + f)*(long)(NJ*ND) + d;
        float hv[NJ];
        #pragma unroll
        for (int j = 0; j < NJ; ++j) hv[j] = hcol[j*ND];
        unsigned mb = mbuf[frame0 + f];
        #pragma unroll
        for (int j = 0; j < NJ; ++j)
            hv[j] = (mb >> j & 1) ? hv[j] : 0.f;
        float acc[NP];
        acc[0] = ((hv[0]+hv[1]) + (hv[2]+hv[3])) + hv[4];
        acc[1] = (hv[5]+hv[6]) + (hv[11]+hv[12]);
        acc[2] = hv[5]+hv[7]+hv[9];
        acc[3] = hv[6]+hv[8]+hv[10];
        acc[4] = hv[11]+hv[13]+hv[15];
        acc[5] = hv[12]+hv[14]+hv[16];
        const unsigned pm[NP] = {0x1Fu, 0x1860u, 0x2A0u, 0x540u, 0xA800u, 0x15000u};
        #pragma unroll
        for (int p = 0; p < NP; ++p) {
            float cnt = (float)__popc(mb & pm[p]);
            s_pool[(f*NP+p)*TSTR + d] = __float2bfloat16(acc[p] / fmaxf(cnt, 1e-6f));
        }
    }
    bsync();   // B1

    // ---- Stage 2: tok + q,k,v (double-buffered B prefetch, 2 tiles in flight) ----
    {
        const int col = w*16 + l15;
        short8v bA[4], bB[4];
        #pragma unroll
        for (int ks = 0; ks < 4; ++ks) bA[ks] = ldB(wgt + WS_WP, w, ks, lane);
        #pragma unroll
        for (int ks = 0; ks < 4; ++ks) bB[ks] = ldB(wgt + WS_WC, w, ks, lane);   // q
        // tok (bA)
        {
            f32x4 a0 = (f32x4)(0.f), a1 = (f32x4)(0.f);
            #pragma unroll
            for (int ks = 0; ks < 4; ++ks) {
                a0 = MFMA(ldsA(s_pool, 0, ks, lane), bA[ks], a0);
                a1 = MFMA(ldsA(s_pool, 1, ks, lane), bA[ks], a1);
            }
            st24(s_tokp, a0, a1, b_proj[col], col, lhi);
        }
        #pragma unroll
        for (int ks = 0; ks < 4; ++ks) bA[ks] = ldB(wgt + WS_WC, 8 + w, ks, lane);  // k
        // q (bB)
        {
            f32x4 a0 = (f32x4)(0.f), a1 = (f32x4)(0.f);
            #pragma unroll
            for (int ks = 0; ks < 4; ++ks) {
                a0 = MFMA(ldsA(s_pool, 0, ks, lane), bB[ks], a0);
                a1 = MFMA(ldsA(s_pool, 1, ks, lane), bB[ks], a1);
            }
            st24(s_q, a0, a1, bc[w*16 + l15], col, lhi);
        }
        #pragma unroll
        for (int ks = 0; ks < 4; ++ks) bB[ks] = ldB(wgt + WS_WC, 16 + w, ks, lane); // v
        // k (bA)
        {
            f32x4 a0 = (f32x4)(0.f), a1 = (f32x4)(0.f);
            #pragma unroll
            for (int ks = 0; ks < 4; ++ks) {
                a0 = MFMA(ldsA(s_pool, 0, ks, lane), bA[ks], a0);
                a1 = MFMA(ldsA(s_pool, 1, ks, lane), bA[ks], a1);
            }
            st24(s_k, a0, a1, bc[(8+w)*16 + l15], col, lhi);
        }
        // v (bB)
        {
            f32x4 a0 = (f32x4)(0.f), a1 = (f32x4)(0.f);
            #pragma unroll
            for (int ks = 0; ks < 4; ++ks) {
                a0 = MFMA(ldsA(s_pool, 0, ks, lane), bB[ks], a0);
                a1 = MFMA(ldsA(s_pool, 1, ks, lane), bB[ks], a1);
            }
            st24(s_v, a0, a1, bc[(16+w)*16 + l15], col, lhi);
        }
    }
    bsync();   // B2

    // ---- prefetch out-proj B tile; stays in flight across B3 (bsync, no vmcnt drain)
    short8v bo[4];
    #pragma unroll
    for (int ks = 0; ks < 4; ++ks) bo[ks] = ldB(wgt + WS_WO, w, ks, lane);

    // ---- Stage 3 (waves 0..3, wave fq owns frame fq): MFMA scores + wave-parallel
    //      softmax + importance + PV, all intra-wave (WFENCE only) ----
    if (w < NG) {
        const int fq = w;
        float* s_pr = s_probs + fq*(NH*NP*NP);
        const int arow = (fq*NP + (l15 > 5 ? 5 : l15))*TSTR + (lhi << 3);
        float imp = 0.f;
        #pragma unroll
        for (int h = 0; h < NH; ++h) {
            short8v qa = *reinterpret_cast<const short8v*>(s_q + arow + h*32);
            short8v kb = *reinterpret_cast<const short8v*>(s_k + arow + h*32);
            f32x4 c = MFMA(qa, kb, (f32x4)(0.f));
            #pragma unroll
            for (int j = 0; j < 4; ++j) {
                int q = lhi*4 + j;
                float sc  = c[j] * 0.17677669529663688f;     // 1/sqrt(32)
                float scm = (l15 < NP) ? sc : -1e30f;
                scm = fmaxf(scm, __shfl_xor(scm, 1));
                scm = fmaxf(scm, __shfl_xor(scm, 2));
                scm = fmaxf(scm, __shfl_xor(scm, 4));
                scm = fmaxf(scm, __shfl_xor(scm, 8));
                float e = (l15 < NP) ? __expf(sc - scm) : 0.f;
                float den = e;
                den += __shfl_xor(den, 1);
                den += __shfl_xor(den, 2);
                den += __shfl_xor(den, 4);
                den += __shfl_xor(den, 8);
                float p = e / den;
                if (q < NP) {
                    imp += p;                                 // p==0 for l15>=6
                    if (l15 < NP) s_pr[(h*NP + q)*NP + l15] = p;
                }
            }
        }
        imp += __shfl_xor(imp, 16);
        imp += __shfl_xor(imp, 32);
        if (lane < NP)
            out[(long)NBT*NP*ND + (frame0 + fq)*NP + lane] = imp * (1.f/24.f);
        WFENCE();   // P visible within wave
        // PV: lane owns cols c0,c0+1 (head h = lane>>4); o over dead q rows
        {
            const int c0 = lane*2;
            const int h  = lane >> 4;
            const float* pr = s_pr + h*NP*NP;
            float vx[NP], vy[NP];
            #pragma unroll
            for (int pk = 0; pk < NP; ++pk) {
                unsigned vv = *reinterpret_cast<const unsigned*>(&s_v[(fq*NP+pk)*TSTR + c0]);
                vx[pk] = bf2f((unsigned short)(vv & 0xFFFF));
                vy[pk] = bf2f((unsigned short)(vv >> 16));
            }
            #pragma unroll
            for (int qi = 0; qi < NP; ++qi) {
                const float* pq = pr + qi*NP;
                float ox = pq[0]*vx[0]+pq[1]*vx[1]+pq[2]*vx[2]
                         + pq[3]*vx[3]+pq[4]*vx[4]+pq[5]*vx[5];
                float oy = pq[0]*vy[0]+pq[1]*vy[1]+pq[2]*vy[2]
                         + pq[3]*vy[3]+pq[4]*vy[4]+pq[5]*vy[5];
                *reinterpret_cast<unsigned*>(&s_q[(fq*NP+qi)*TSTR + c0]) = pk2(ox, oy);
            }
        }
    }
    bsync();   // B3

    // ---- Stage 4: y = o @ Wo^T + b_out + tok -> fp32 y over dead k|v ----
    {
        f32x4 a0 = (f32x4)(0.f), a1 = (f32x4)(0.f);
        #pragma unroll
        for (int ks = 0; ks < 4; ++ks) {
            a0 = MFMA(ldsA(s_q, 0, ks, lane), bo[ks], a0);
            a1 = MFMA(ldsA(s_q, 1, ks, lane), bo[ks], a1);
        }
        int col = w*16 + l15;
        float bv = b_out[col];
        #pragma unroll
        for (int j = 0; j < 4; ++j) {
            int r0 = lhi*4 + j;
            float res0 = bf2f(*reinterpret_cast<const unsigned short*>(&s_tokp[r0*TSTR + col]));
            s_y[r0*YSTR + col] = a0[j] + bv + res0;
            int r1 = 16 + lhi*4 + j;
            if (r1 < NTOK) {
                float res1 = bf2f(*reinterpret_cast<const unsigned short*>(&s_tokp[r1*TSTR + col]));
                s_y[r1*YSTR + col] = a1[j] + bv + res1;
            }
        }
    }
    bsync();   // B4

    // ---- Stage 5: LayerNorm stats (4 lanes per token) ----
    if (tid < NTOK*4) {   // 96 threads
        int token = tid >> 2, sub = tid & 3;
        const float* row = s_y + token*YSTR + sub*32;
        float s = 0.f, s2 = 0.f;
        #pragma unroll
        for (int j = 0; j < 32; j += 4) {
            float4 v = *reinterpret_cast<const float4*>(row + j);
            s  += v.x + v.y + v.z + v.w;
            s2 += v.x*v.x + v.y*v.y + v.z*v.z + v.w*v.w;
        }
        s  += __shfl_xor(s, 1);  s  += __shfl_xor(s, 2);
        s2 += __shfl_xor(s2, 1); s2 += __shfl_xor(s2, 2);
        float mean = s * (1.f/128.f);
        float var  = s2 * (1.f/128.f) - mean*mean;
        if (sub == 0) {
            s_mu[token]  = mean;
            s_inv[token] = rsqrtf(var + 1e-5f);
        }
    }
    bsync();   // B5

    // ---- Stage 6: normalize + coalesced store ----
    #pragma unroll
    for (int i = 0; i < 2; ++i) {
        int idx4 = i*NTHR + tid;
        if (idx4 < NTOK*(ND/4)) {
            int token = idx4 >> 5;
            int dj = (idx4 & 31) << 2;
            float mean = s_mu[token], inv = s_inv[token];
            float4 v = *reinterpret_cast<const float4*>(s_y + token*YSTR + dj);
            float4 g = *reinterpret_cast<const float4*>(ln_g + dj);
            float4 b = *reinterpret_cast<const float4*>(ln_b + dj);
            float4 r;
            r.x = (v.x-mean)*inv*g.x + b.x;
            r.y = (v.y-mean)*inv*g.y + b.y;
            r.z = (v.z-mean)*inv*g.z + b.z;
            r.w = (v.w-mean)*inv*g.w + b.w;
            *reinterpret_cast<float4*>(out + (frame0*NP + token)*(long)ND + dj) = r;
        }
    }
}

extern "C" void kernel_launch(void* const* d_in, const int* in_sizes, int n_in,
                              void* d_out, int out_size, void* d_ws, size_t ws_size,
                              hipStream_t stream) {
    const float* h_joint = (const float*)d_in[0];
    const float* mask    = (const float*)d_in[1];
    const float* W_proj  = (const float*)d_in[2];
    const float* b_proj  = (const float*)d_in[3];
    const float* W_in    = (const float*)d_in[4];
    const float* b_in    = (const float*)d_in[5];
    const float* W_out   = (const float*)d_in[6];
    const float* b_out   = (const float*)d_in[7];
    const float* ln_g    = (const float*)d_in[8];
    const float* ln_b    = (const float*)d_in[9];
    float* out = (float*)d_out;
    bf16*     wgt  = (bf16*)d_ws;
    float*    bc   = (float*)((char*)d_ws + WS_BC);
    unsigned* mbuf = (unsigned*)((char*)d_ws + WS_MB);

    hipLaunchKernelGGL(prep, dim3(640), dim3(128), 0, stream,
                       W_proj, W_in, W_out, b_proj, b_in, mask, wgt, bc, mbuf);
    hipLaunchKernelGGL(bpa_fused, dim3(GRID), dim3(NTHR), 0, stream,
                       h_joint, wgt, bc, mbuf, b_proj, b_out, ln_g, ln_b, out);
}